// Round 1
// baseline (473.307 us; speedup 1.0000x reference)
//
#include <hip/hip_runtime.h>
#include <hip/hip_bf16.h>
#include <cstdint>

#define DEVINL __device__ __forceinline__

typedef __attribute__((ext_vector_type(8))) short bf16x8;
typedef __attribute__((ext_vector_type(4))) float f32x4;

DEVINL unsigned short f2bf(float f) {
    union { float f; unsigned u; } v; v.f = f;
    unsigned r = v.u + 0x7fffu + ((v.u >> 16) & 1u);   // RNE
    return (unsigned short)(r >> 16);
}
DEVINL float bf2f(unsigned short h) {
    union { unsigned u; float f; } v; v.u = ((unsigned)h) << 16;
    return v.f;
}

constexpr int BM = 128, BN = 128, BK = 32;
constexpr int PITCH = 40;   // bf16 elems per LDS row = 80B (16B aligned, 2-way bank pattern)
constexpr int NSP = 256;    // H*W

// Y^T[b][n][m] = sigmoid( sum_k W[b][m][k] * X[b][..] + bias[b][m] )
// A-operand = W tile [BM][BK] (K-contiguous), B-operand = X^T tile [BN][BK] (K-contiguous).
// B_F32_NT: X is fp32 [b][K][256] (layer 1, transpose in staging); else bf16 [b][256][K].
template<bool B_F32_NT>
__global__ __launch_bounds__(256, 2)
void fc_gemm(const float* __restrict__ Wt, const float* __restrict__ bias,
             const void* __restrict__ Xv, unsigned short* __restrict__ Yt,
             int M, int K)
{
    const int b  = blockIdx.y;
    const int nt = blockIdx.x & 1;       // 2 N-tiles (256/128)
    const int mt = blockIdx.x >> 1;
    const int n0 = nt * BN;
    const int m0 = mt * BM;

    __shared__ __align__(16) unsigned short sA[2][BM * PITCH];
    __shared__ __align__(16) unsigned short sB[2][BN * PITCH];

    const int tid  = threadIdx.x;
    const int lane = tid & 63;
    const int wm   = ((tid >> 6) >> 1) * 64;   // wave row offset (2x2 waves)
    const int wn   = ((tid >> 6) & 1) * 64;
    const int fr   = lane & 15;
    const int fo   = (lane >> 4) * 8;          // k-offset of this lane's 8 contiguous elems

    // A staging: 128x32 fp32, thread loads 4x float4 (coalesced along K)
    const int ar = tid >> 3;             // 0..31
    const int ac = (tid & 7) * 4;        // 0..28
    const float* Wb = Wt + (size_t)b * M * K + (size_t)m0 * K;

    // B staging coords
    const float*          Xf = (const float*)Xv;          // [K][256] (layer 1)
    const unsigned short* Xh = (const unsigned short*)Xv; // [256][K] (layers 2+)
    const int brow = tid >> 2, bcol = (tid & 3) * 8;      // contig: 64 rows/iter, 16B chunks
    const int bk = tid >> 5,  bn = (tid & 31) * 4;        // NT: 8 k-rows/iter, float4 along n

    float4 aR[4];
    float4 bRn[4];
    uint4  bRc[2];

    auto loadA = [&](int k0) {
#pragma unroll
        for (int i = 0; i < 4; ++i)
            aR[i] = *(const float4*)(Wb + (size_t)(ar + 32*i) * K + k0 + ac);
    };
    auto loadB = [&](int k0) {
        if constexpr (B_F32_NT) {
#pragma unroll
            for (int i = 0; i < 4; ++i)
                bRn[i] = *(const float4*)(Xf + (size_t)b*K*NSP + (size_t)(k0 + bk + 8*i)*NSP + n0 + bn);
        } else {
#pragma unroll
            for (int i = 0; i < 2; ++i)
                bRc[i] = *(const uint4*)(Xh + ((size_t)b*NSP + n0 + brow + 64*i)*K + k0 + bcol);
        }
    };
    auto storeA = [&](int buf) {
#pragma unroll
        for (int i = 0; i < 4; ++i) {
            ushort4 p;
            p.x = f2bf(aR[i].x); p.y = f2bf(aR[i].y);
            p.z = f2bf(aR[i].z); p.w = f2bf(aR[i].w);
            *(ushort4*)&sA[buf][(ar + 32*i) * PITCH + ac] = p;
        }
    };
    auto storeB = [&](int buf) {
        if constexpr (B_F32_NT) {
            // transpose fp32 [k][n] -> LDS [n][k] bf16 (scalar writes)
#pragma unroll
            for (int i = 0; i < 4; ++i) {
                const int kk = bk + 8*i;
                sB[buf][(bn+0)*PITCH + kk] = f2bf(bRn[i].x);
                sB[buf][(bn+1)*PITCH + kk] = f2bf(bRn[i].y);
                sB[buf][(bn+2)*PITCH + kk] = f2bf(bRn[i].z);
                sB[buf][(bn+3)*PITCH + kk] = f2bf(bRn[i].w);
            }
        } else {
#pragma unroll
            for (int i = 0; i < 2; ++i)
                *(uint4*)&sB[buf][(brow + 64*i) * PITCH + bcol] = bRc[i];
        }
    };

    f32x4 acc[4][4] = {};

    loadA(0); loadB(0);
    storeA(0); storeB(0);
    __syncthreads();

    const int NT = K / BK;
    int cur = 0;
#pragma unroll 1
    for (int t = 0; t < NT; ++t) {
        if (t + 1 < NT) { loadA((t+1)*BK); loadB((t+1)*BK); }  // issue early; hides under MFMA

        bf16x8 af[4], bfr[4];
#pragma unroll
        for (int i = 0; i < 4; ++i)
            af[i] = *(const bf16x8*)&sA[cur][(wm + i*16 + fr) * PITCH + fo];
#pragma unroll
        for (int i = 0; i < 4; ++i)
            bfr[i] = *(const bf16x8*)&sB[cur][(wn + i*16 + fr) * PITCH + fo];
#pragma unroll
        for (int mi = 0; mi < 4; ++mi)
#pragma unroll
            for (int ni = 0; ni < 4; ++ni)
                acc[mi][ni] = __builtin_amdgcn_mfma_f32_16x16x32_bf16(af[mi], bfr[ni], acc[mi][ni], 0, 0, 0);

        if (t + 1 < NT) { storeA(cur ^ 1); storeB(cur ^ 1); }  // other buffer: no pre-barrier needed
        __syncthreads();
        cur ^= 1;
    }

    // Epilogue: D col = lane&15 (n), rows = (lane>>4)*4+q (m). Store Y^T[b][n][m] bf16.
#pragma unroll
    for (int mi = 0; mi < 4; ++mi) {
#pragma unroll
        for (int ni = 0; ni < 4; ++ni) {
            const int n  = n0 + wn + ni*16 + fr;
            const int mb = m0 + wm + mi*16 + (lane >> 4) * 4;
            f32x4 v = acc[mi][ni];
            ushort4 o;
#pragma unroll
            for (int q = 0; q < 4; ++q) {
                float y = v[q] + bias[(size_t)b*M + mb + q];
                y = 1.0f / (1.0f + __expf(-y));
                ((unsigned short*)&o)[q] = f2bf(y);
            }
            *(ushort4*)&Yt[((size_t)b*NSP + n)*M + mb] = o;
        }
    }
}

// Layer 5: out[b][n] = sum_k act4T[b][n][k] * w5[b][k] + b5[b]   (no sigmoid)
__global__ void fc_final(const unsigned short* __restrict__ A4,
                         const float* __restrict__ W5,
                         const float* __restrict__ B5,
                         float* __restrict__ out)
{
    const int b = blockIdx.x;
    const int t = threadIdx.x;  // 0..255 spatial
    const unsigned short* row = A4 + ((size_t)b * NSP + t) * 128;
    const float* w = W5 + (size_t)b * 128;
    float acc = B5[b];
#pragma unroll
    for (int k = 0; k < 128; k += 8) {
        uint4 v = *(const uint4*)(row + k);
        acc += bf2f((unsigned short)(v.x & 0xffff)) * w[k+0];
        acc += bf2f((unsigned short)(v.x >> 16))    * w[k+1];
        acc += bf2f((unsigned short)(v.y & 0xffff)) * w[k+2];
        acc += bf2f((unsigned short)(v.y >> 16))    * w[k+3];
        acc += bf2f((unsigned short)(v.z & 0xffff)) * w[k+4];
        acc += bf2f((unsigned short)(v.z >> 16))    * w[k+5];
        acc += bf2f((unsigned short)(v.w & 0xffff)) * w[k+6];
        acc += bf2f((unsigned short)(v.w >> 16))    * w[k+7];
    }
    out[b * NSP + t] = acc;
}

extern "C" void kernel_launch(void* const* d_in, const int* in_sizes, int n_in,
                              void* d_out, int out_size, void* d_ws, size_t ws_size,
                              hipStream_t stream)
{
    const float* x  = (const float*)d_in[0];
    const float* w1 = (const float*)d_in[1];
    const float* b1 = (const float*)d_in[2];
    const float* w2 = (const float*)d_in[3];
    const float* b2 = (const float*)d_in[4];
    const float* w3 = (const float*)d_in[5];
    const float* b3 = (const float*)d_in[6];
    const float* w4 = (const float*)d_in[7];
    const float* b4 = (const float*)d_in[8];
    const float* w5 = (const float*)d_in[9];
    const float* b5 = (const float*)d_in[10];

    // ws layout (bf16 activations, transposed [b][n][dout]); ping-pong regions:
    //   region0 @ 0        : act1 (33.55MB) -> later act3 (8.39MB)
    //   region1 @ 16.78M u16: act2 (16.78MB) -> later act4 (4.19MB)
    unsigned short* ws0  = (unsigned short*)d_ws;
    unsigned short* act1 = ws0;
    unsigned short* act2 = ws0 + (size_t)64 * 256 * 1024;
    unsigned short* act3 = ws0;                            // act1 dead after L2
    unsigned short* act4 = ws0 + (size_t)64 * 256 * 1024;  // act2 dead after L3

    dim3 blk(256);
    fc_gemm<true ><<<dim3(16, 64), blk, 0, stream>>>(w1, b1, x,    act1, 1024, 2048);
    fc_gemm<false><<<dim3( 8, 64), blk, 0, stream>>>(w2, b2, act1, act2,  512, 1024);
    fc_gemm<false><<<dim3( 4, 64), blk, 0, stream>>>(w3, b3, act2, act3,  256,  512);
    fc_gemm<false><<<dim3( 2, 64), blk, 0, stream>>>(w4, b4, act3, act4,  128,  256);
    fc_final<<<dim3(64), blk, 0, stream>>>(act4, w5, b5, (float*)d_out);
}